// Round 3
// baseline (1837.882 us; speedup 1.0000x reference)
//
#include <hip/hip_runtime.h>
#include <cmath>
#include <algorithm>

#define NLEVELS 16

typedef float v4f __attribute__((ext_vector_type(4)));

struct LevelMeta {
  float scale;       // f32(BASE_RES * GROWTH^l - 1.0)
  unsigned stride;   // res+1 (dense levels)
  unsigned offset;   // entry offset into table
  unsigned mask;     // params-1 (hashed levels; params == 2^22)
  int hashed;
};
struct MetaPack { LevelMeta m[NLEVELS]; };

// ---------------------------------------------------------------------------
// Stage 1: hashgrid encode. One thread per (level, point): 8.4M threads,
// no LDS, no h[64] array -> 28 VGPR, 85% occupancy, maximum memory-level
// parallelism for the random hashed-table gathers. Measured 495us @ 3.4TB/s
// (near the random-64B-line HBM roofline; fetch ~= structural floor).
// ---------------------------------------------------------------------------
__global__ __launch_bounds__(256) void hg_encode_kernel(
    const float* __restrict__ x,
    const float* __restrict__ table,
    v4f* __restrict__ hb,
    MetaPack mp, int N, int pblocks)
{
  const int l = blockIdx.x / pblocks;
  const int p = (blockIdx.x - l * pblocks) * 256 + threadIdx.x;
  if (p >= N) return;

  const float    scale  = mp.m[l].scale;
  const unsigned stride = mp.m[l].stride;
  const unsigned offset = mp.m[l].offset;
  const unsigned mask   = mp.m[l].mask;
  const int      hashed = mp.m[l].hashed;

  const float px = x[3 * p + 0];
  const float py = x[3 * p + 1];
  const float pz = x[3 * p + 2];

  const float posx = px * scale + 0.5f;
  const float posy = py * scale + 0.5f;
  const float posz = pz * scale + 0.5f;
  const float flx = floorf(posx), fly = floorf(posy), flz = floorf(posz);
  const float fx = posx - flx, fy = posy - fly, fz = posz - flz;
  const unsigned bx = (unsigned)flx, by = (unsigned)fly, bz = (unsigned)flz;

  unsigned idx[8];
  if (hashed) {
    #pragma unroll
    for (int c = 0; c < 8; ++c) {
      const unsigned cx = bx + (c & 1);
      const unsigned cy = by + ((c >> 1) & 1);
      const unsigned cz = bz + ((c >> 2) & 1);
      idx[c] = ((cx ^ (cy * 2654435761u) ^ (cz * 805459861u)) & mask) + offset;
    }
  } else {
    #pragma unroll
    for (int c = 0; c < 8; ++c) {
      const unsigned cx = bx + (c & 1);
      const unsigned cy = by + ((c >> 1) & 1);
      const unsigned cz = bz + ((c >> 2) & 1);
      idx[c] = cx + cy * stride + cz * stride * stride + offset;
    }
  }

  v4f f[8];
  #pragma unroll
  for (int c = 0; c < 8; ++c)
    f[c] = ((const v4f*)table)[idx[c]];

  const float wx0 = 1.0f - fx, wx1 = fx;
  const float wy0 = 1.0f - fy, wy1 = fy;
  const float wz0 = 1.0f - fz, wz1 = fz;

  v4f acc = (v4f){0.f, 0.f, 0.f, 0.f};
  #pragma unroll
  for (int c = 0; c < 8; ++c) {
    const float w = ((c & 1) ? wx1 : wx0) *
                    ((c & 2) ? wy1 : wy0) *
                    ((c & 4) ? wz1 : wz0);
    acc += w * f[c];
  }

  __builtin_nontemporal_store(acc, &hb[(size_t)l * N + p]);
}

// ---------------------------------------------------------------------------
// Stage 2: MLP. One thread per point. The previous version (Hs[64][128],
// 32KB LDS) capped residency at 10 waves/CU -> scalar weight-load latency
// exposed (~450us inferred vs ~55us VALU floor). This version stages only
// neurons 0..31 through LDS (16KB) and keeps neurons 32..63 in 32 registers:
// VGPR ~115 (<=128 via __launch_bounds__(128,4)) and 16KB LDS -> 8 blocks/CU
// = 16 waves/CU, doubling latency hiding. Per-lane LDS column is stride-1 ->
// conflict-free, no barrier (each thread touches only its own column).
// ---------------------------------------------------------------------------
__global__ __launch_bounds__(128, 4) void mlp_kernel(
    const v4f* __restrict__ hb,
    const float* __restrict__ W0,
    const float* __restrict__ W1,
    const float* __restrict__ W2,
    float* __restrict__ out,
    int N)
{
  __shared__ float Hs[32 * 128];   // 16 KB
  const int t = threadIdx.x;
  const int p = blockIdx.x * 128 + t;
  if (p >= N) return;

  float h[64];
  #pragma unroll
  for (int l = 0; l < NLEVELS; ++l) {
    const v4f v = __builtin_nontemporal_load(&hb[(size_t)l * N + p]);
    h[4 * l + 0] = v.x;
    h[4 * l + 1] = v.y;
    h[4 * l + 2] = v.z;
    h[4 * l + 3] = v.w;
  }

  float r[32];

  // ---- Layer 0: h1 = relu(h @ W0^T); j<32 -> LDS, j>=32 -> regs ----
  #pragma unroll 2
  for (int j = 0; j < 64; ++j) {
    const float* __restrict__ wr = W0 + j * 64;  // wave-uniform -> s_load
    float a0 = 0.f, a1 = 0.f, a2 = 0.f, a3 = 0.f;
    #pragma unroll
    for (int k = 0; k < 64; k += 4) {
      a0 += wr[k + 0] * h[k + 0];
      a1 += wr[k + 1] * h[k + 1];
      a2 += wr[k + 2] * h[k + 2];
      a3 += wr[k + 3] * h[k + 3];
    }
    const float v = fmaxf((a0 + a1) + (a2 + a3), 0.f);
    if (j < 32) Hs[j * 128 + t] = v;
    else        r[j - 32] = v;
  }
  #pragma unroll
  for (int k = 0; k < 32; ++k) h[k] = Hs[k * 128 + t];
  #pragma unroll
  for (int k = 0; k < 32; ++k) h[32 + k] = r[k];

  // ---- Layer 1: h2 = relu(h1 @ W1^T); same split ----
  #pragma unroll 2
  for (int j = 0; j < 64; ++j) {
    const float* __restrict__ wr = W1 + j * 64;
    float a0 = 0.f, a1 = 0.f, a2 = 0.f, a3 = 0.f;
    #pragma unroll
    for (int k = 0; k < 64; k += 4) {
      a0 += wr[k + 0] * h[k + 0];
      a1 += wr[k + 1] * h[k + 1];
      a2 += wr[k + 2] * h[k + 2];
      a3 += wr[k + 3] * h[k + 3];
    }
    const float v = fmaxf((a0 + a1) + (a2 + a3), 0.f);
    if (j < 32) Hs[j * 128 + t] = v;
    else        r[j - 32] = v;
  }
  #pragma unroll
  for (int k = 0; k < 32; ++k) h[k] = Hs[k * 128 + t];
  #pragma unroll
  for (int k = 0; k < 32; ++k) h[32 + k] = r[k];

  // ---- Layer 2: out = h2 @ W2^T ----
  {
    float a0 = 0.f, a1 = 0.f, a2 = 0.f, a3 = 0.f;
    #pragma unroll
    for (int k = 0; k < 64; k += 4) {
      a0 += W2[k + 0] * h[k + 0];
      a1 += W2[k + 1] * h[k + 1];
      a2 += W2[k + 2] * h[k + 2];
      a3 += W2[k + 3] * h[k + 3];
    }
    out[p] = (a0 + a1) + (a2 + a3);
  }
}

// ---------------------------------------------------------------------------
// Fallback: fused kernel (used only if workspace too small).
// ---------------------------------------------------------------------------
__global__ __launch_bounds__(128, 2) void sdf_fused_kernel(
    const float* __restrict__ x,
    const float* __restrict__ table,
    const float* __restrict__ W0,
    const float* __restrict__ W1,
    const float* __restrict__ W2,
    float* __restrict__ out,
    MetaPack mp, int N)
{
  __shared__ float Hs[64 * 128];
  const int t = threadIdx.x;
  const int p = blockIdx.x * 128 + t;
  if (p >= N) return;

  const float px = x[3 * p + 0];
  const float py = x[3 * p + 1];
  const float pz = x[3 * p + 2];

  float h[64];

  #pragma unroll
  for (int l = 0; l < NLEVELS; ++l) {
    const float    scale  = mp.m[l].scale;
    const unsigned stride = mp.m[l].stride;
    const unsigned offset = mp.m[l].offset;
    const unsigned mask   = mp.m[l].mask;
    const int      hashed = mp.m[l].hashed;

    const float posx = px * scale + 0.5f;
    const float posy = py * scale + 0.5f;
    const float posz = pz * scale + 0.5f;
    const float flx = floorf(posx), fly = floorf(posy), flz = floorf(posz);
    const float fx = posx - flx, fy = posy - fly, fz = posz - flz;
    const unsigned bx = (unsigned)flx, by = (unsigned)fly, bz = (unsigned)flz;

    unsigned idx[8];
    if (hashed) {
      #pragma unroll
      for (int c = 0; c < 8; ++c) {
        const unsigned cx = bx + (c & 1);
        const unsigned cy = by + ((c >> 1) & 1);
        const unsigned cz = bz + ((c >> 2) & 1);
        idx[c] = ((cx ^ (cy * 2654435761u) ^ (cz * 805459861u)) & mask) + offset;
      }
    } else {
      #pragma unroll
      for (int c = 0; c < 8; ++c) {
        const unsigned cx = bx + (c & 1);
        const unsigned cy = by + ((c >> 1) & 1);
        const unsigned cz = bz + ((c >> 2) & 1);
        idx[c] = cx + cy * stride + cz * stride * stride + offset;
      }
    }

    float4 f[8];
    #pragma unroll
    for (int c = 0; c < 8; ++c)
      f[c] = ((const float4*)table)[idx[c]];

    const float wx0 = 1.0f - fx, wx1 = fx;
    const float wy0 = 1.0f - fy, wy1 = fy;
    const float wz0 = 1.0f - fz, wz1 = fz;

    float a0 = 0.f, a1 = 0.f, a2 = 0.f, a3 = 0.f;
    #pragma unroll
    for (int c = 0; c < 8; ++c) {
      const float w = ((c & 1) ? wx1 : wx0) *
                      ((c & 2) ? wy1 : wy0) *
                      ((c & 4) ? wz1 : wz0);
      a0 += w * f[c].x;
      a1 += w * f[c].y;
      a2 += w * f[c].z;
      a3 += w * f[c].w;
    }
    h[4 * l + 0] = a0;
    h[4 * l + 1] = a1;
    h[4 * l + 2] = a2;
    h[4 * l + 3] = a3;
  }

  #pragma unroll 2
  for (int j = 0; j < 64; ++j) {
    const float* __restrict__ wr = W0 + j * 64;
    float a0 = 0.f, a1 = 0.f, a2 = 0.f, a3 = 0.f;
    #pragma unroll
    for (int k = 0; k < 64; k += 4) {
      a0 += wr[k + 0] * h[k + 0];
      a1 += wr[k + 1] * h[k + 1];
      a2 += wr[k + 2] * h[k + 2];
      a3 += wr[k + 3] * h[k + 3];
    }
    Hs[j * 128 + t] = fmaxf((a0 + a1) + (a2 + a3), 0.f);
  }
  #pragma unroll
  for (int k = 0; k < 64; ++k) h[k] = Hs[k * 128 + t];

  #pragma unroll 2
  for (int j = 0; j < 64; ++j) {
    const float* __restrict__ wr = W1 + j * 64;
    float a0 = 0.f, a1 = 0.f, a2 = 0.f, a3 = 0.f;
    #pragma unroll
    for (int k = 0; k < 64; k += 4) {
      a0 += wr[k + 0] * h[k + 0];
      a1 += wr[k + 1] * h[k + 1];
      a2 += wr[k + 2] * h[k + 2];
      a3 += wr[k + 3] * h[k + 3];
    }
    Hs[j * 128 + t] = fmaxf((a0 + a1) + (a2 + a3), 0.f);
  }
  #pragma unroll
  for (int k = 0; k < 64; ++k) h[k] = Hs[k * 128 + t];

  {
    float a0 = 0.f, a1 = 0.f, a2 = 0.f, a3 = 0.f;
    #pragma unroll
    for (int k = 0; k < 64; k += 4) {
      a0 += W2[k + 0] * h[k + 0];
      a1 += W2[k + 1] * h[k + 1];
      a2 += W2[k + 2] * h[k + 2];
      a3 += W2[k + 3] * h[k + 3];
    }
    out[p] = (a0 + a1) + (a2 + a3);
  }
}

extern "C" void kernel_launch(void* const* d_in, const int* in_sizes, int n_in,
                              void* d_out, int out_size, void* d_ws, size_t ws_size,
                              hipStream_t stream)
{
  const float* x  = (const float*)d_in[0];
  const float* tb = (const float*)d_in[1];
  const float* W0 = (const float*)d_in[2];
  const float* W1 = (const float*)d_in[3];
  const float* W2 = (const float*)d_in[4];
  float* out = (float*)d_out;
  const int N = out_size;  // output is (N, 1)

  // Replicate the reference's level metadata in double precision.
  MetaPack mp;
  const double growth = std::exp((std::log(2048.0) - std::log(16.0)) / 15.0);
  unsigned long long offset = 0;
  for (int l = 0; l < NLEVELS; ++l) {
    const double scale = 16.0 * std::pow(growth, (double)l) - 1.0;
    const int res = (int)std::ceil(scale) + 1;
    const long long cube = (long long)(res + 1) * (res + 1) * (res + 1);
    long long params = std::min((long long)(1 << 22), cube);
    params = ((params + 7) / 8) * 8;
    const bool dense = (cube <= params);
    mp.m[l].scale  = (float)scale;
    mp.m[l].stride = (unsigned)(res + 1);
    mp.m[l].offset = (unsigned)offset;
    mp.m[l].mask   = (unsigned)(params - 1);
    mp.m[l].hashed = dense ? 0 : 1;
    offset += (unsigned long long)params;
  }

  const size_t need = (size_t)N * 64 * sizeof(float);  // 128 MiB at N=524288
  if (d_ws != nullptr && ws_size >= need) {
    const int pblocks = (N + 255) / 256;
    hipLaunchKernelGGL(hg_encode_kernel, dim3(NLEVELS * pblocks), dim3(256), 0,
                       stream, x, tb, (v4f*)d_ws, mp, N, pblocks);
    hipLaunchKernelGGL(mlp_kernel, dim3((N + 127) / 128), dim3(128), 0, stream,
                       (const v4f*)d_ws, W0, W1, W2, out, N);
  } else {
    const int grid = (N + 127) / 128;
    hipLaunchKernelGGL(sdf_fused_kernel, dim3(grid), dim3(128), 0, stream,
                       x, tb, W0, W1, W2, out, mp, N);
  }
}

// Round 4
// 1381.459 us; speedup vs baseline: 1.3304x; 1.3304x over previous
//
#include <hip/hip_runtime.h>
#include <cmath>
#include <algorithm>

#define NLEVELS 16

typedef float v4f __attribute__((ext_vector_type(4)));

struct LevelMeta {
  float scale;       // f32(BASE_RES * GROWTH^l - 1.0)
  unsigned stride;   // res+1 (dense levels)
  unsigned offset;   // entry offset into table
  unsigned mask;     // params-1 (hashed levels; params == 2^22)
  int hashed;
};
struct MetaPack { LevelMeta m[NLEVELS]; };

// ---------------------------------------------------------------------------
// Stage 1: hashgrid encode. One thread per (level, point): 8.4M threads,
// no LDS, no h[64] array -> 28 VGPR, 85% occupancy, maximum memory-level
// parallelism for the random hashed-table gathers. Measured 495us @ 3.4TB/s;
// FETCH 1.51GB == structural floor (8 hashed levels x ~6 distinct 64B
// lines/point), so this kernel is at the random-gather HBM roofline.
// ---------------------------------------------------------------------------
__global__ __launch_bounds__(256) void hg_encode_kernel(
    const float* __restrict__ x,
    const float* __restrict__ table,
    v4f* __restrict__ hb,
    MetaPack mp, int N, int pblocks)
{
  const int l = blockIdx.x / pblocks;
  const int p = (blockIdx.x - l * pblocks) * 256 + threadIdx.x;
  if (p >= N) return;

  const float    scale  = mp.m[l].scale;
  const unsigned stride = mp.m[l].stride;
  const unsigned offset = mp.m[l].offset;
  const unsigned mask   = mp.m[l].mask;
  const int      hashed = mp.m[l].hashed;

  const float px = x[3 * p + 0];
  const float py = x[3 * p + 1];
  const float pz = x[3 * p + 2];

  const float posx = px * scale + 0.5f;
  const float posy = py * scale + 0.5f;
  const float posz = pz * scale + 0.5f;
  const float flx = floorf(posx), fly = floorf(posy), flz = floorf(posz);
  const float fx = posx - flx, fy = posy - fly, fz = posz - flz;
  const unsigned bx = (unsigned)flx, by = (unsigned)fly, bz = (unsigned)flz;

  unsigned idx[8];
  if (hashed) {
    #pragma unroll
    for (int c = 0; c < 8; ++c) {
      const unsigned cx = bx + (c & 1);
      const unsigned cy = by + ((c >> 1) & 1);
      const unsigned cz = bz + ((c >> 2) & 1);
      idx[c] = ((cx ^ (cy * 2654435761u) ^ (cz * 805459861u)) & mask) + offset;
    }
  } else {
    #pragma unroll
    for (int c = 0; c < 8; ++c) {
      const unsigned cx = bx + (c & 1);
      const unsigned cy = by + ((c >> 1) & 1);
      const unsigned cz = bz + ((c >> 2) & 1);
      idx[c] = cx + cy * stride + cz * stride * stride + offset;
    }
  }

  v4f f[8];
  #pragma unroll
  for (int c = 0; c < 8; ++c)
    f[c] = ((const v4f*)table)[idx[c]];

  const float wx0 = 1.0f - fx, wx1 = fx;
  const float wy0 = 1.0f - fy, wy1 = fy;
  const float wz0 = 1.0f - fz, wz1 = fz;

  v4f acc = (v4f){0.f, 0.f, 0.f, 0.f};
  #pragma unroll
  for (int c = 0; c < 8; ++c) {
    const float w = ((c & 1) ? wx1 : wx0) *
                    ((c & 2) ? wy1 : wy0) *
                    ((c & 4) ? wz1 : wz0);
    acc += w * f[c];
  }

  __builtin_nontemporal_store(acc, &hb[(size_t)l * N + p]);
}

// ---------------------------------------------------------------------------
// Stage 2: MLP. One thread per point, h[64] in VGPRs (64x reuse demands
// register residency). Layer outputs: neurons 0..31 staged through a 16KB
// LDS buffer, neurons 32..63 kept in r[32] registers.
//
// Occupancy derivation (round-3 post-mortem): __launch_bounds__(X, w) caps
// VGPR at 256/w -- (128,4) forced a 64-VGPR cap and spilled h[]/r[] to
// scratch (VGPR_Count=64, WRITE_SIZE=1.4GB, 747us). Use (128,2): cap 128,
// fits the ~112 live floats with no spill. HW: 128 VGPR -> 4 waves/SIMD
// (512-reg physical pool), LDS 16KB -> 10 blocks/CU; binding = VGPR at
// 16 waves/CU (vs 10 when Hs was 32KB). LDS [neuron][thread] layout:
// per-lane stride-1 column -> 2 lanes/bank (free), no barrier needed.
// ---------------------------------------------------------------------------
__global__ __launch_bounds__(128, 2) void mlp_kernel(
    const v4f* __restrict__ hb,
    const float* __restrict__ W0,
    const float* __restrict__ W1,
    const float* __restrict__ W2,
    float* __restrict__ out,
    int N)
{
  __shared__ float Hs[32 * 128];   // 16 KB
  const int t = threadIdx.x;
  const int p = blockIdx.x * 128 + t;
  if (p >= N) return;

  float h[64];
  #pragma unroll
  for (int l = 0; l < NLEVELS; ++l) {
    const v4f v = __builtin_nontemporal_load(&hb[(size_t)l * N + p]);
    h[4 * l + 0] = v.x;
    h[4 * l + 1] = v.y;
    h[4 * l + 2] = v.z;
    h[4 * l + 3] = v.w;
  }

  float r[32];

  // ---- Layer 0: h1 = relu(h @ W0^T) ----
  #pragma unroll 2
  for (int j = 0; j < 32; ++j) {
    const float* __restrict__ wr = W0 + j * 64;  // wave-uniform -> s_load
    float a0 = 0.f, a1 = 0.f, a2 = 0.f, a3 = 0.f;
    #pragma unroll
    for (int k = 0; k < 64; k += 4) {
      a0 += wr[k + 0] * h[k + 0];
      a1 += wr[k + 1] * h[k + 1];
      a2 += wr[k + 2] * h[k + 2];
      a3 += wr[k + 3] * h[k + 3];
    }
    Hs[j * 128 + t] = fmaxf((a0 + a1) + (a2 + a3), 0.f);
  }
  #pragma unroll 2
  for (int j = 32; j < 64; ++j) {
    const float* __restrict__ wr = W0 + j * 64;
    float a0 = 0.f, a1 = 0.f, a2 = 0.f, a3 = 0.f;
    #pragma unroll
    for (int k = 0; k < 64; k += 4) {
      a0 += wr[k + 0] * h[k + 0];
      a1 += wr[k + 1] * h[k + 1];
      a2 += wr[k + 2] * h[k + 2];
      a3 += wr[k + 3] * h[k + 3];
    }
    r[j - 32] = fmaxf((a0 + a1) + (a2 + a3), 0.f);
  }
  #pragma unroll
  for (int k = 0; k < 32; ++k) h[k] = Hs[k * 128 + t];
  #pragma unroll
  for (int k = 0; k < 32; ++k) h[32 + k] = r[k];

  // ---- Layer 1: h2 = relu(h1 @ W1^T) ----
  #pragma unroll 2
  for (int j = 0; j < 32; ++j) {
    const float* __restrict__ wr = W1 + j * 64;
    float a0 = 0.f, a1 = 0.f, a2 = 0.f, a3 = 0.f;
    #pragma unroll
    for (int k = 0; k < 64; k += 4) {
      a0 += wr[k + 0] * h[k + 0];
      a1 += wr[k + 1] * h[k + 1];
      a2 += wr[k + 2] * h[k + 2];
      a3 += wr[k + 3] * h[k + 3];
    }
    Hs[j * 128 + t] = fmaxf((a0 + a1) + (a2 + a3), 0.f);
  }
  #pragma unroll 2
  for (int j = 32; j < 64; ++j) {
    const float* __restrict__ wr = W1 + j * 64;
    float a0 = 0.f, a1 = 0.f, a2 = 0.f, a3 = 0.f;
    #pragma unroll
    for (int k = 0; k < 64; k += 4) {
      a0 += wr[k + 0] * h[k + 0];
      a1 += wr[k + 1] * h[k + 1];
      a2 += wr[k + 2] * h[k + 2];
      a3 += wr[k + 3] * h[k + 3];
    }
    r[j - 32] = fmaxf((a0 + a1) + (a2 + a3), 0.f);
  }
  #pragma unroll
  for (int k = 0; k < 32; ++k) h[k] = Hs[k * 128 + t];
  #pragma unroll
  for (int k = 0; k < 32; ++k) h[32 + k] = r[k];

  // ---- Layer 2: out = h2 @ W2^T ----
  {
    float a0 = 0.f, a1 = 0.f, a2 = 0.f, a3 = 0.f;
    #pragma unroll
    for (int k = 0; k < 64; k += 4) {
      a0 += W2[k + 0] * h[k + 0];
      a1 += W2[k + 1] * h[k + 1];
      a2 += W2[k + 2] * h[k + 2];
      a3 += W2[k + 3] * h[k + 3];
    }
    out[p] = (a0 + a1) + (a2 + a3);
  }
}

// ---------------------------------------------------------------------------
// Fallback: fused kernel (used only if workspace too small).
// ---------------------------------------------------------------------------
__global__ __launch_bounds__(128, 2) void sdf_fused_kernel(
    const float* __restrict__ x,
    const float* __restrict__ table,
    const float* __restrict__ W0,
    const float* __restrict__ W1,
    const float* __restrict__ W2,
    float* __restrict__ out,
    MetaPack mp, int N)
{
  __shared__ float Hs[64 * 128];
  const int t = threadIdx.x;
  const int p = blockIdx.x * 128 + t;
  if (p >= N) return;

  const float px = x[3 * p + 0];
  const float py = x[3 * p + 1];
  const float pz = x[3 * p + 2];

  float h[64];

  #pragma unroll
  for (int l = 0; l < NLEVELS; ++l) {
    const float    scale  = mp.m[l].scale;
    const unsigned stride = mp.m[l].stride;
    const unsigned offset = mp.m[l].offset;
    const unsigned mask   = mp.m[l].mask;
    const int      hashed = mp.m[l].hashed;

    const float posx = px * scale + 0.5f;
    const float posy = py * scale + 0.5f;
    const float posz = pz * scale + 0.5f;
    const float flx = floorf(posx), fly = floorf(posy), flz = floorf(posz);
    const float fx = posx - flx, fy = posy - fly, fz = posz - flz;
    const unsigned bx = (unsigned)flx, by = (unsigned)fly, bz = (unsigned)flz;

    unsigned idx[8];
    if (hashed) {
      #pragma unroll
      for (int c = 0; c < 8; ++c) {
        const unsigned cx = bx + (c & 1);
        const unsigned cy = by + ((c >> 1) & 1);
        const unsigned cz = bz + ((c >> 2) & 1);
        idx[c] = ((cx ^ (cy * 2654435761u) ^ (cz * 805459861u)) & mask) + offset;
      }
    } else {
      #pragma unroll
      for (int c = 0; c < 8; ++c) {
        const unsigned cx = bx + (c & 1);
        const unsigned cy = by + ((c >> 1) & 1);
        const unsigned cz = bz + ((c >> 2) & 1);
        idx[c] = cx + cy * stride + cz * stride * stride + offset;
      }
    }

    float4 f[8];
    #pragma unroll
    for (int c = 0; c < 8; ++c)
      f[c] = ((const float4*)table)[idx[c]];

    const float wx0 = 1.0f - fx, wx1 = fx;
    const float wy0 = 1.0f - fy, wy1 = fy;
    const float wz0 = 1.0f - fz, wz1 = fz;

    float a0 = 0.f, a1 = 0.f, a2 = 0.f, a3 = 0.f;
    #pragma unroll
    for (int c = 0; c < 8; ++c) {
      const float w = ((c & 1) ? wx1 : wx0) *
                      ((c & 2) ? wy1 : wy0) *
                      ((c & 4) ? wz1 : wz0);
      a0 += w * f[c].x;
      a1 += w * f[c].y;
      a2 += w * f[c].z;
      a3 += w * f[c].w;
    }
    h[4 * l + 0] = a0;
    h[4 * l + 1] = a1;
    h[4 * l + 2] = a2;
    h[4 * l + 3] = a3;
  }

  #pragma unroll 2
  for (int j = 0; j < 64; ++j) {
    const float* __restrict__ wr = W0 + j * 64;
    float a0 = 0.f, a1 = 0.f, a2 = 0.f, a3 = 0.f;
    #pragma unroll
    for (int k = 0; k < 64; k += 4) {
      a0 += wr[k + 0] * h[k + 0];
      a1 += wr[k + 1] * h[k + 1];
      a2 += wr[k + 2] * h[k + 2];
      a3 += wr[k + 3] * h[k + 3];
    }
    Hs[j * 128 + t] = fmaxf((a0 + a1) + (a2 + a3), 0.f);
  }
  #pragma unroll
  for (int k = 0; k < 64; ++k) h[k] = Hs[k * 128 + t];

  #pragma unroll 2
  for (int j = 0; j < 64; ++j) {
    const float* __restrict__ wr = W1 + j * 64;
    float a0 = 0.f, a1 = 0.f, a2 = 0.f, a3 = 0.f;
    #pragma unroll
    for (int k = 0; k < 64; k += 4) {
      a0 += wr[k + 0] * h[k + 0];
      a1 += wr[k + 1] * h[k + 1];
      a2 += wr[k + 2] * h[k + 2];
      a3 += wr[k + 3] * h[k + 3];
    }
    Hs[j * 128 + t] = fmaxf((a0 + a1) + (a2 + a3), 0.f);
  }
  #pragma unroll
  for (int k = 0; k < 64; ++k) h[k] = Hs[k * 128 + t];

  {
    float a0 = 0.f, a1 = 0.f, a2 = 0.f, a3 = 0.f;
    #pragma unroll
    for (int k = 0; k < 64; k += 4) {
      a0 += W2[k + 0] * h[k + 0];
      a1 += W2[k + 1] * h[k + 1];
      a2 += W2[k + 2] * h[k + 2];
      a3 += W2[k + 3] * h[k + 3];
    }
    out[p] = (a0 + a1) + (a2 + a3);
  }
}

extern "C" void kernel_launch(void* const* d_in, const int* in_sizes, int n_in,
                              void* d_out, int out_size, void* d_ws, size_t ws_size,
                              hipStream_t stream)
{
  const float* x  = (const float*)d_in[0];
  const float* tb = (const float*)d_in[1];
  const float* W0 = (const float*)d_in[2];
  const float* W1 = (const float*)d_in[3];
  const float* W2 = (const float*)d_in[4];
  float* out = (float*)d_out;
  const int N = out_size;  // output is (N, 1)

  // Replicate the reference's level metadata in double precision.
  MetaPack mp;
  const double growth = std::exp((std::log(2048.0) - std::log(16.0)) / 15.0);
  unsigned long long offset = 0;
  for (int l = 0; l < NLEVELS; ++l) {
    const double scale = 16.0 * std::pow(growth, (double)l) - 1.0;
    const int res = (int)std::ceil(scale) + 1;
    const long long cube = (long long)(res + 1) * (res + 1) * (res + 1);
    long long params = std::min((long long)(1 << 22), cube);
    params = ((params + 7) / 8) * 8;
    const bool dense = (cube <= params);
    mp.m[l].scale  = (float)scale;
    mp.m[l].stride = (unsigned)(res + 1);
    mp.m[l].offset = (unsigned)offset;
    mp.m[l].mask   = (unsigned)(params - 1);
    mp.m[l].hashed = dense ? 0 : 1;
    offset += (unsigned long long)params;
  }

  const size_t need = (size_t)N * 64 * sizeof(float);  // 128 MiB at N=524288
  if (d_ws != nullptr && ws_size >= need) {
    const int pblocks = (N + 255) / 256;
    hipLaunchKernelGGL(hg_encode_kernel, dim3(NLEVELS * pblocks), dim3(256), 0,
                       stream, x, tb, (v4f*)d_ws, mp, N, pblocks);
    hipLaunchKernelGGL(mlp_kernel, dim3((N + 127) / 128), dim3(128), 0, stream,
                       (const v4f*)d_ws, W0, W1, W2, out, N);
  } else {
    const int grid = (N + 127) / 128;
    hipLaunchKernelGGL(sdf_fused_kernel, dim3(grid), dim3(128), 0, stream,
                       x, tb, W0, W1, W2, out, mp, N);
  }
}

// Round 5
// 1374.920 us; speedup vs baseline: 1.3367x; 1.0048x over previous
//
#include <hip/hip_runtime.h>
#include <cmath>
#include <algorithm>

#define NLEVELS 16

typedef float v4f __attribute__((ext_vector_type(4)));

struct LevelMeta {
  float scale;       // f32(BASE_RES * GROWTH^l - 1.0)
  unsigned stride;   // res+1 (dense levels)
  unsigned offset;   // entry offset into table
  unsigned mask;     // params-1 (hashed levels; params == 2^22)
  int hashed;
};
struct MetaPack { LevelMeta m[NLEVELS]; };

// ---------------------------------------------------------------------------
// Stage 1: hashgrid encode. One thread per (level, point): 8.4M threads,
// no LDS, no h[64] array -> 28 VGPR, 86% occupancy. Measured 497us @ 3.4TB/s;
// FETCH 1.51GB ~= structural floor for random 64B-line gathers -> at the
// random-access HBM roofline. Unchanged.
// ---------------------------------------------------------------------------
__global__ __launch_bounds__(256) void hg_encode_kernel(
    const float* __restrict__ x,
    const float* __restrict__ table,
    v4f* __restrict__ hb,
    MetaPack mp, int N, int pblocks)
{
  const int l = blockIdx.x / pblocks;
  const int p = (blockIdx.x - l * pblocks) * 256 + threadIdx.x;
  if (p >= N) return;

  const float    scale  = mp.m[l].scale;
  const unsigned stride = mp.m[l].stride;
  const unsigned offset = mp.m[l].offset;
  const unsigned mask   = mp.m[l].mask;
  const int      hashed = mp.m[l].hashed;

  const float px = x[3 * p + 0];
  const float py = x[3 * p + 1];
  const float pz = x[3 * p + 2];

  const float posx = px * scale + 0.5f;
  const float posy = py * scale + 0.5f;
  const float posz = pz * scale + 0.5f;
  const float flx = floorf(posx), fly = floorf(posy), flz = floorf(posz);
  const float fx = posx - flx, fy = posy - fly, fz = posz - flz;
  const unsigned bx = (unsigned)flx, by = (unsigned)fly, bz = (unsigned)flz;

  unsigned idx[8];
  if (hashed) {
    #pragma unroll
    for (int c = 0; c < 8; ++c) {
      const unsigned cx = bx + (c & 1);
      const unsigned cy = by + ((c >> 1) & 1);
      const unsigned cz = bz + ((c >> 2) & 1);
      idx[c] = ((cx ^ (cy * 2654435761u) ^ (cz * 805459861u)) & mask) + offset;
    }
  } else {
    #pragma unroll
    for (int c = 0; c < 8; ++c) {
      const unsigned cx = bx + (c & 1);
      const unsigned cy = by + ((c >> 1) & 1);
      const unsigned cz = bz + ((c >> 2) & 1);
      idx[c] = cx + cy * stride + cz * stride * stride + offset;
    }
  }

  v4f f[8];
  #pragma unroll
  for (int c = 0; c < 8; ++c)
    f[c] = ((const v4f*)table)[idx[c]];

  const float wx0 = 1.0f - fx, wx1 = fx;
  const float wy0 = 1.0f - fy, wy1 = fy;
  const float wz0 = 1.0f - fz, wz1 = fz;

  v4f acc = (v4f){0.f, 0.f, 0.f, 0.f};
  #pragma unroll
  for (int c = 0; c < 8; ++c) {
    const float w = ((c & 1) ? wx1 : wx0) *
                    ((c & 2) ? wy1 : wy0) *
                    ((c & 4) ? wz1 : wz0);
    acc += w * f[c];
  }

  __builtin_nontemporal_store(acc, &hb[(size_t)l * N + p]);
}

// ---------------------------------------------------------------------------
// Stage 2: MLP, weight-stationary wave-GEMM.
//
// Round-4 diagnosis: per-point layout keeps each neuron's 64-float weight
// row in SGPRs (one row = 64 of ~102 SGPRs -> no double-buffering), so every
// neuron pays an exposed ~250cy SMEM wait vs 128cy of FMA -> ~5x over VALU
// floor. Here lane j owns neuron j: weight row in 64 VGPRs, loaded once per
// layer per wave (L1-resident vector loads). Activations live in per-wave-
// private LDS [p][68] (pad 68: transposed writes land 2 lanes/bank = free;
// fill writes spread over all 32 banks). Activation reads are wave-uniform
// ds_read_b128 -> pure broadcast, conflict-free. Each wave processes 8
// points: per layer 128 ds_read + 512 FMA per lane -> VALU-dominated.
// Layer 2 = per-point 64-lane __shfl_xor butterfly reduce.
// VGPR ~100 (cap 128 via (256,2), no spill), LDS 17408B/block.
// ---------------------------------------------------------------------------
__global__ __launch_bounds__(256, 2) void mlp_kernel(
    const v4f* __restrict__ hb,
    const float* __restrict__ W0,
    const float* __restrict__ W1,
    const float* __restrict__ W2,
    float* __restrict__ out,
    int N)
{
  // 4 waves * 2 buffers * 8 points * 68 floats = 17408 B
  __shared__ float ls[4 * 2 * 8 * 68];
  const int tid  = threadIdx.x;
  const int lane = tid & 63;
  const int wave = tid >> 6;
  float* __restrict__ h0 = &ls[wave * (2 * 8 * 68)];
  float* __restrict__ h1 = h0 + 8 * 68;

  const int pbase = blockIdx.x * 32 + wave * 8;

  // ---- Fill h0: 8 points x 16 levels (v4f each) from hb[l][N] ----
  #pragma unroll
  for (int t = 0; t < 2; ++t) {
    const int flat = t * 64 + lane;   // 0..127
    const int l = flat >> 3;          // 0..15
    const int p = flat & 7;           // 0..7
    const int gp = pbase + p;
    v4f v = (v4f){0.f, 0.f, 0.f, 0.f};
    if (gp < N) v = hb[(size_t)l * N + gp];
    *(v4f*)&h0[p * 68 + l * 4] = v;
  }

  // ---- Load W0 row for this lane's neuron into VGPRs ----
  float w[64];
  {
    const v4f* __restrict__ wr = (const v4f*)(W0 + lane * 64);
    #pragma unroll
    for (int q = 0; q < 16; ++q) {
      const v4f wv = wr[q];
      w[4 * q + 0] = wv.x; w[4 * q + 1] = wv.y;
      w[4 * q + 2] = wv.z; w[4 * q + 3] = wv.w;
    }
  }

  __syncthreads();

  // ---- Layer 0: lane j computes relu(dot(h0[p], W0[j])) for 8 points ----
  float acc[8];
  #pragma unroll
  for (int p = 0; p < 8; ++p) {
    float a = 0.f;
    #pragma unroll
    for (int q = 0; q < 16; ++q) {
      const v4f hv = *(const v4f*)&h0[p * 68 + q * 4];   // broadcast
      a += hv.x * w[4 * q + 0];
      a += hv.y * w[4 * q + 1];
      a += hv.z * w[4 * q + 2];
      a += hv.w * w[4 * q + 3];
    }
    acc[p] = fmaxf(a, 0.f);
  }

  // transpose: h1[p][j] = acc[p]  (lanes j consecutive -> 2 lanes/bank, free)
  #pragma unroll
  for (int p = 0; p < 8; ++p) h1[p * 68 + lane] = acc[p];

  // ---- Load W1 row (overwrites w[]) ----
  {
    const v4f* __restrict__ wr = (const v4f*)(W1 + lane * 64);
    #pragma unroll
    for (int q = 0; q < 16; ++q) {
      const v4f wv = wr[q];
      w[4 * q + 0] = wv.x; w[4 * q + 1] = wv.y;
      w[4 * q + 2] = wv.z; w[4 * q + 3] = wv.w;
    }
  }

  __syncthreads();

  // ---- Layer 1 ----
  float acc2[8];
  #pragma unroll
  for (int p = 0; p < 8; ++p) {
    float a = 0.f;
    #pragma unroll
    for (int q = 0; q < 16; ++q) {
      const v4f hv = *(const v4f*)&h1[p * 68 + q * 4];   // broadcast
      a += hv.x * w[4 * q + 0];
      a += hv.y * w[4 * q + 1];
      a += hv.z * w[4 * q + 2];
      a += hv.w * w[4 * q + 3];
    }
    acc2[p] = fmaxf(a, 0.f);
  }

  // ---- Layer 2: out[p] = sum_j acc2[p] * W2[j] (butterfly over 64 lanes) --
  const float w2 = W2[lane];
  float myout = 0.f;
  #pragma unroll
  for (int p = 0; p < 8; ++p) {
    float v = acc2[p] * w2;
    v += __shfl_xor(v, 1);
    v += __shfl_xor(v, 2);
    v += __shfl_xor(v, 4);
    v += __shfl_xor(v, 8);
    v += __shfl_xor(v, 16);
    v += __shfl_xor(v, 32);
    if (lane == p) myout = v;
  }
  if (lane < 8 && (pbase + lane) < N) out[pbase + lane] = myout;
}

// ---------------------------------------------------------------------------
// Fallback: fused kernel (used only if workspace too small).
// ---------------------------------------------------------------------------
__global__ __launch_bounds__(128, 2) void sdf_fused_kernel(
    const float* __restrict__ x,
    const float* __restrict__ table,
    const float* __restrict__ W0,
    const float* __restrict__ W1,
    const float* __restrict__ W2,
    float* __restrict__ out,
    MetaPack mp, int N)
{
  __shared__ float Hs[64 * 128];
  const int t = threadIdx.x;
  const int p = blockIdx.x * 128 + t;
  if (p >= N) return;

  const float px = x[3 * p + 0];
  const float py = x[3 * p + 1];
  const float pz = x[3 * p + 2];

  float h[64];

  #pragma unroll
  for (int l = 0; l < NLEVELS; ++l) {
    const float    scale  = mp.m[l].scale;
    const unsigned stride = mp.m[l].stride;
    const unsigned offset = mp.m[l].offset;
    const unsigned mask   = mp.m[l].mask;
    const int      hashed = mp.m[l].hashed;

    const float posx = px * scale + 0.5f;
    const float posy = py * scale + 0.5f;
    const float posz = pz * scale + 0.5f;
    const float flx = floorf(posx), fly = floorf(posy), flz = floorf(posz);
    const float fx = posx - flx, fy = posy - fly, fz = posz - flz;
    const unsigned bx = (unsigned)flx, by = (unsigned)fly, bz = (unsigned)flz;

    unsigned idx[8];
    if (hashed) {
      #pragma unroll
      for (int c = 0; c < 8; ++c) {
        const unsigned cx = bx + (c & 1);
        const unsigned cy = by + ((c >> 1) & 1);
        const unsigned cz = bz + ((c >> 2) & 1);
        idx[c] = ((cx ^ (cy * 2654435761u) ^ (cz * 805459861u)) & mask) + offset;
      }
    } else {
      #pragma unroll
      for (int c = 0; c < 8; ++c) {
        const unsigned cx = bx + (c & 1);
        const unsigned cy = by + ((c >> 1) & 1);
        const unsigned cz = bz + ((c >> 2) & 1);
        idx[c] = cx + cy * stride + cz * stride * stride + offset;
      }
    }

    float4 f[8];
    #pragma unroll
    for (int c = 0; c < 8; ++c)
      f[c] = ((const float4*)table)[idx[c]];

    const float wx0 = 1.0f - fx, wx1 = fx;
    const float wy0 = 1.0f - fy, wy1 = fy;
    const float wz0 = 1.0f - fz, wz1 = fz;

    float a0 = 0.f, a1 = 0.f, a2 = 0.f, a3 = 0.f;
    #pragma unroll
    for (int c = 0; c < 8; ++c) {
      const float w = ((c & 1) ? wx1 : wx0) *
                      ((c & 2) ? wy1 : wy0) *
                      ((c & 4) ? wz1 : wz0);
      a0 += w * f[c].x;
      a1 += w * f[c].y;
      a2 += w * f[c].z;
      a3 += w * f[c].w;
    }
    h[4 * l + 0] = a0;
    h[4 * l + 1] = a1;
    h[4 * l + 2] = a2;
    h[4 * l + 3] = a3;
  }

  #pragma unroll 2
  for (int j = 0; j < 64; ++j) {
    const float* __restrict__ wr = W0 + j * 64;
    float a0 = 0.f, a1 = 0.f, a2 = 0.f, a3 = 0.f;
    #pragma unroll
    for (int k = 0; k < 64; k += 4) {
      a0 += wr[k + 0] * h[k + 0];
      a1 += wr[k + 1] * h[k + 1];
      a2 += wr[k + 2] * h[k + 2];
      a3 += wr[k + 3] * h[k + 3];
    }
    Hs[j * 128 + t] = fmaxf((a0 + a1) + (a2 + a3), 0.f);
  }
  #pragma unroll
  for (int k = 0; k < 64; ++k) h[k] = Hs[k * 128 + t];

  #pragma unroll 2
  for (int j = 0; j < 64; ++j) {
    const float* __restrict__ wr = W1 + j * 64;
    float a0 = 0.f, a1 = 0.f, a2 = 0.f, a3 = 0.f;
    #pragma unroll
    for (int k = 0; k < 64; k += 4) {
      a0 += wr[k + 0] * h[k + 0];
      a1 += wr[k + 1] * h[k + 1];
      a2 += wr[k + 2] * h[k + 2];
      a3 += wr[k + 3] * h[k + 3];
    }
    Hs[j * 128 + t] = fmaxf((a0 + a1) + (a2 + a3), 0.f);
  }
  #pragma unroll
  for (int k = 0; k < 64; ++k) h[k] = Hs[k * 128 + t];

  {
    float a0 = 0.f, a1 = 0.f, a2 = 0.f, a3 = 0.f;
    #pragma unroll
    for (int k = 0; k < 64; k += 4) {
      a0 += W2[k + 0] * h[k + 0];
      a1 += W2[k + 1] * h[k + 1];
      a2 += W2[k + 2] * h[k + 2];
      a3 += W2[k + 3] * h[k + 3];
    }
    out[p] = (a0 + a1) + (a2 + a3);
  }
}

extern "C" void kernel_launch(void* const* d_in, const int* in_sizes, int n_in,
                              void* d_out, int out_size, void* d_ws, size_t ws_size,
                              hipStream_t stream)
{
  const float* x  = (const float*)d_in[0];
  const float* tb = (const float*)d_in[1];
  const float* W0 = (const float*)d_in[2];
  const float* W1 = (const float*)d_in[3];
  const float* W2 = (const float*)d_in[4];
  float* out = (float*)d_out;
  const int N = out_size;  // output is (N, 1)

  // Replicate the reference's level metadata in double precision.
  MetaPack mp;
  const double growth = std::exp((std::log(2048.0) - std::log(16.0)) / 15.0);
  unsigned long long offset = 0;
  for (int l = 0; l < NLEVELS; ++l) {
    const double scale = 16.0 * std::pow(growth, (double)l) - 1.0;
    const int res = (int)std::ceil(scale) + 1;
    const long long cube = (long long)(res + 1) * (res + 1) * (res + 1);
    long long params = std::min((long long)(1 << 22), cube);
    params = ((params + 7) / 8) * 8;
    const bool dense = (cube <= params);
    mp.m[l].scale  = (float)scale;
    mp.m[l].stride = (unsigned)(res + 1);
    mp.m[l].offset = (unsigned)offset;
    mp.m[l].mask   = (unsigned)(params - 1);
    mp.m[l].hashed = dense ? 0 : 1;
    offset += (unsigned long long)params;
  }

  const size_t need = (size_t)N * 64 * sizeof(float);  // 128 MiB at N=524288
  if (d_ws != nullptr && ws_size >= need) {
    const int pblocks = (N + 255) / 256;
    hipLaunchKernelGGL(hg_encode_kernel, dim3(NLEVELS * pblocks), dim3(256), 0,
                       stream, x, tb, (v4f*)d_ws, mp, N, pblocks);
    const int mblocks = (N + 31) / 32;   // 32 points per 256-thread block
    hipLaunchKernelGGL(mlp_kernel, dim3(mblocks), dim3(256), 0, stream,
                       (const v4f*)d_ws, W0, W1, W2, out, N);
  } else {
    const int grid = (N + 127) / 128;
    hipLaunchKernelGGL(sdf_fused_kernel, dim3(grid), dim3(128), 0, stream,
                       x, tb, W0, W1, W2, out, mp, N);
  }
}